// Round 9
// baseline (620.896 us; speedup 1.0000x reference)
//
#include <hip/hip_runtime.h>
#include <hip/hip_bf16.h>
#include <stdint.h>

#define N_TOK 4096   // B*S
#define KF    8192   // IN_F
#define NF    8192   // OUT_F

#define BM 256
#define BN 256

typedef __attribute__((ext_vector_type(8))) short short8;
typedef __attribute__((ext_vector_type(16))) float f32x16;

#define GLOBAL_P(p) ((const __attribute__((address_space(1))) void*)(p))
#define LDS_P(p)    ((__attribute__((address_space(3))) void*)(p))

// ---------- pass 1: int8-quantize activations, store as bf16 (exact) ----------
__global__ void quant_x(const float* __restrict__ x, const float* __restrict__ scale_p,
                        uint16_t* __restrict__ a) {
    const float s = *scale_p;
    const int n8 = N_TOK * KF / 8;
    const int stride = gridDim.x * blockDim.x;
    for (int i = blockIdx.x * blockDim.x + threadIdx.x; i < n8; i += stride) {
        const float4* xp = (const float4*)(x + (size_t)i * 8);
        float4 v0 = xp[0], v1 = xp[1];
        float q[8] = {v0.x, v0.y, v0.z, v0.w, v1.x, v1.y, v1.z, v1.w};
        union { uint16_t u16[8]; short8 v; } o;
        #pragma unroll
        for (int j = 0; j < 8; ++j) {
            float t = rintf(q[j] / s);
            t = fminf(fmaxf(t, -128.f), 127.f);
            union { float f; uint32_t u; } cv; cv.f = t;
            o.u16[j] = (uint16_t)(cv.u >> 16);
        }
        *(short8*)(a + (size_t)i * 8) = o.v;
    }
}

// ---------- pass 2: unpack nibbles + signs -> bf16 weights (exact powers of 2) ----------
__global__ void dequant_w(const int* __restrict__ packed, const int* __restrict__ signs,
                          const int* __restrict__ minexp_p, uint16_t* __restrict__ w) {
    const int me = *minexp_p;
    const int ebase = (me + 127) << 7;
    const int n4 = NF * (KF / 2) / 4;
    const int stride = gridDim.x * blockDim.x;
    for (int i = blockIdx.x * blockDim.x + threadIdx.x; i < n4; i += stride) {
        int4 p  = ((const int4*)packed)[i];
        int4 s0 = ((const int4*)signs)[(size_t)i * 2];
        int4 s1 = ((const int4*)signs)[(size_t)i * 2 + 1];
        int pw[4] = {p.x, p.y, p.z, p.w};
        int sg[8] = {s0.x, s0.y, s0.z, s0.w, s1.x, s1.y, s1.z, s1.w};
        union { uint16_t u16[8]; short8 v; } o;
        #pragma unroll
        for (int j = 0; j < 4; ++j) {
            int lo = pw[j] & 0xF, hi = (pw[j] >> 4) & 0xF;
            o.u16[2 * j]     = (uint16_t)((ebase + (lo << 7)) | (sg[2 * j]     < 0 ? 0x8000 : 0));
            o.u16[2 * j + 1] = (uint16_t)((ebase + (hi << 7)) | (sg[2 * j + 1] < 0 ? 0x8000 : 0));
        }
        *(short8*)(w + (size_t)i * 8) = o.v;
    }
}

// ---------- pass 3: 256x256-tile bf16 GEMM, 32x32x16 MFMA, 1 barrier/Kh window ----------
// out[M,N] = A[M,K] * W[N,K]^T * s + bias
// Round-8-verified window/ring/vmcnt skeleton; MFMA shape switched to 32x32x16
// (2382 vs 2075 TF ceiling, half the instructions). New LDS swizzle for 32-row
// b128 reads: o ^= ((o>>7)&3)<<4  (col bits 4-5 ^= row bits 1-2) -> each bank
// gets exactly 4 dwords per wave read (theoretical minimum for b128).
#define BARRIER()  __builtin_amdgcn_s_barrier()
#define SCHED0()   __builtin_amdgcn_sched_barrier(0)
#define WAITVM4()  do { asm volatile("s_waitcnt vmcnt(4)"); SCHED0(); } while (0)
#define WAITVM0()  do { asm volatile("s_waitcnt vmcnt(0)"); SCHED0(); } while (0)
#define SP1 __builtin_amdgcn_s_setprio(1)
#define SP0 __builtin_amdgcn_s_setprio(0)

#define SWZ(o) ((o) ^ ((((o) >> 7) & 3) << 4))

__global__ __launch_bounds__(512, 2) void gemm_bt(
        const uint16_t* __restrict__ A, const uint16_t* __restrict__ W,
        const float* __restrict__ bias, const float* __restrict__ scale_p,
        float* __restrict__ out) {
    // 4-slot K-half ring per operand: slot = 256 rows x 32 cols bf16 = 16 KiB
    __shared__ uint16_t ldsA[4 * 256 * 32];   // 64 KiB
    __shared__ uint16_t ldsB[4 * 256 * 32];   // 64 KiB

    const int tid  = threadIdx.x;
    const int wid  = tid >> 6, lane = tid & 63;
    const int wr = wid >> 2, wc = wid & 3;         // 2x4 wave grid; wave tile 128x64
    const int rlane = lane & 31, khalf = lane >> 5;

    // XCD-region mapping (round-3, verified: FETCH 2.1GB -> 453MB)
    const int bid = blockIdx.x;        // 0..511
    const int xcd = bid & 7;
    const int i_l = bid >> 3;          // 0..63
    const int gen = i_l >> 5;          // 0,1
    const int il  = i_l & 31;          // 0..31
    const int by  = gen * 8 + (il >> 2);   // 0..15
    const int bx  = xcd * 4 + (il & 3);    // 0..31
    const int rowA0 = by * BM;
    const int colB0 = bx * BN;

    // staging: LDS physical o = (q*512+tid)*16 linear; global source pre-swizzled
    const int o0 = tid * 16, o1 = (512 + tid) * 16;
    const int l0 = SWZ(o0);
    const int l1 = SWZ(o1);
    const char* gA0 = (const char*)A + ((size_t)(rowA0 + (l0 >> 6)) * KF) * 2 + (l0 & 63);
    const char* gA1 = (const char*)A + ((size_t)(rowA0 + (l1 >> 6)) * KF) * 2 + (l1 & 63);
    const char* gB0 = (const char*)W + ((size_t)(colB0 + (l0 >> 6)) * KF) * 2 + (l0 & 63);
    const char* gB1 = (const char*)W + ((size_t)(colB0 + (l1 >> 6)) * KF) * 2 + (l1 & 63);
    const int ldst0 = wid * 1024;
    const int ldst1 = 8192 + wid * 1024;

    // fragment read offsets (swizzled): A row = wr*128 + m*32 + rlane, m=0..3;
    // B row(out-col) = wc*64 + n*32 + rlane, n=0..1; colbyte = kstep*32 + khalf*16.
    int aoff[8], boff[4];
    #pragma unroll
    for (int ks = 0; ks < 2; ++ks) {
        const int cb = ks * 32 + khalf * 16;
        #pragma unroll
        for (int m = 0; m < 4; ++m) {
            int o = (wr * 128 + m * 32 + rlane) * 64 + cb;
            aoff[ks * 4 + m] = SWZ(o);
        }
        #pragma unroll
        for (int n = 0; n < 2; ++n) {
            int o = (wc * 64 + n * 32 + rlane) * 64 + cb;
            boff[ks * 2 + n] = SWZ(o);
        }
    }

#define STAGE_A(j) do { \
    char* b_ = (char*)ldsA + ((j) & 3) * 16384; \
    __builtin_amdgcn_global_load_lds(GLOBAL_P(gA0 + (size_t)(j) * 64), LDS_P(b_ + ldst0), 16, 0, 0); \
    __builtin_amdgcn_global_load_lds(GLOBAL_P(gA1 + (size_t)(j) * 64), LDS_P(b_ + ldst1), 16, 0, 0); \
} while (0)
#define STAGE_B(j) do { \
    char* b_ = (char*)ldsB + ((j) & 3) * 16384; \
    __builtin_amdgcn_global_load_lds(GLOBAL_P(gB0 + (size_t)(j) * 64), LDS_P(b_ + ldst0), 16, 0, 0); \
    __builtin_amdgcn_global_load_lds(GLOBAL_P(gB1 + (size_t)(j) * 64), LDS_P(b_ + ldst1), 16, 0, 0); \
} while (0)
#define LDA_K(DST, KS, SLOT) do { \
    const char* p_ = (const char*)ldsA + (SLOT) * 16384; \
    _Pragma("unroll") for (int i_ = 0; i_ < 4; ++i_) \
        DST[i_] = *(const short8*)(p_ + aoff[(KS) * 4 + i_]); \
} while (0)
#define LDB_K(DST, KS, SLOT) do { \
    const char* p_ = (const char*)ldsB + (SLOT) * 16384; \
    _Pragma("unroll") for (int i_ = 0; i_ < 2; ++i_) \
        DST[i_] = *(const short8*)(p_ + boff[(KS) * 2 + i_]); \
} while (0)
#define MFMA8(A4, B2) do { \
    SP1; \
    _Pragma("unroll") for (int mm_ = 0; mm_ < 4; ++mm_) \
        _Pragma("unroll") for (int nn_ = 0; nn_ < 2; ++nn_) \
            acc[mm_][nn_] = __builtin_amdgcn_mfma_f32_32x32x16_bf16( \
                A4[mm_], B2[nn_], acc[mm_][nn_], 0, 0, 0); \
    SP0; \
} while (0)

// Window j (cur Kh = slot SC): entering, aP/bP hold cur kstep0 (loaded prev window).
// {BAR; LD cur kstep1; STAGE_A(j+3); 8 MFMA(k0); LD next kstep0; STAGE_B(j+3);
//  8 MFMA(k1); VM4}.  VM4 at END of window j drains Kh(j+2) in every wave BEFORE
// the barrier opening window j+1 -> cross-wave publication safe (round-8 proof).
#define WINDOW(SC, SN, JST, VM) do { \
    BARRIER(); \
    LDA_K(aQ, 1, SC); LDB_K(bQ, 1, SC); \
    STAGE_A(JST); \
    MFMA8(aP, bP); \
    LDA_K(aP, 0, SN); LDB_K(bP, 0, SN); \
    STAGE_B(JST); \
    MFMA8(aQ, bQ); \
    VM; \
} while (0)
#define WINDOW_NS(SC, SN, VM) do { \
    BARRIER(); \
    LDA_K(aQ, 1, SC); LDB_K(bQ, 1, SC); \
    MFMA8(aP, bP); \
    LDA_K(aP, 0, SN); LDB_K(bP, 0, SN); \
    MFMA8(aQ, bQ); \
    VM; \
} while (0)

    f32x16 acc[4][2] = {};
    short8 aP[4], aQ[4], bP[2], bQ[2];

    // ---- prologue: stage Kh0..Kh2 (slots 0,1,2); publish Kh0,Kh1; preload cur k0 ----
    STAGE_A(0); STAGE_B(0);
    STAGE_A(1); STAGE_B(1);
    STAGE_A(2); STAGE_B(2);
    WAITVM4();                 // 12 -> <=4 outstanding: Kh0 AND Kh1 retired (all waves)
    BARRIER();                 // publish Kh0 + Kh1
    LDA_K(aP, 0, 0);
    LDB_K(bP, 0, 0);

    // ---- main loop: windows j = 0..251, 4 per iteration ----
    for (int kt = 0; kt < 63; ++kt) {
        const int j0 = 4 * kt;
        WINDOW(0, 1, j0 + 3, WAITVM4());   // j=j0   : VM4 drains Kh(j0+2)
        WINDOW(1, 2, j0 + 4, WAITVM4());   // j=j0+1
        WINDOW(2, 3, j0 + 5, WAITVM4());   // j=j0+2
        WINDOW(3, 0, j0 + 6, WAITVM4());   // j=j0+3
    }

    // ---- tail: j = 252 (stage Kh255), 253, 254, 255 ----
    WINDOW(0, 1, 255, WAITVM4());          // j=252: VM4 drains Kh254
    WINDOW_NS(1, 2, WAITVM0());            // j=253: VM0 drains Kh255
    WINDOW_NS(2, 3, (void)0);              // j=254
    BARRIER();                             // j=255: MFMA only
    LDA_K(aQ, 1, 3); LDB_K(bQ, 1, 3);
    MFMA8(aP, bP);
    MFMA8(aQ, bQ);

    // ---- epilogue: 32x32 C/D layout col = lane&31, row = (r&3)+8*(r>>2)+4*(lane>>5) ----
    const float s = *scale_p;
    const int colbase = colB0 + wc * 64 + rlane;
    const int rowbase = rowA0 + wr * 128 + 4 * khalf;
    #pragma unroll
    for (int n = 0; n < 2; ++n) {
        const float bv = bias[colbase + n * 32];
        #pragma unroll
        for (int mb = 0; mb < 4; ++mb) {
            #pragma unroll
            for (int r = 0; r < 16; ++r) {
                const int row = rowbase + mb * 32 + (r & 3) + 8 * (r >> 2);
                out[(size_t)row * NF + colbase + n * 32] = acc[mb][n][r] * s + bv;
            }
        }
    }
#undef STAGE_A
#undef STAGE_B
#undef LDA_K
#undef LDB_K
#undef MFMA8
#undef WINDOW
#undef WINDOW_NS
}

extern "C" void kernel_launch(void* const* d_in, const int* in_sizes, int n_in,
                              void* d_out, int out_size, void* d_ws, size_t ws_size,
                              hipStream_t stream) {
    const float* x      = (const float*)d_in[0];
    const int*   packed = (const int*)d_in[1];
    const int*   signs  = (const int*)d_in[2];
    const float* bias   = (const float*)d_in[3];
    const float* scale  = (const float*)d_in[4];
    const int*   minexp = (const int*)d_in[5];
    float* out = (float*)d_out;

    uint16_t* A = (uint16_t*)d_ws;                                       // 64 MiB
    uint16_t* W = (uint16_t*)((char*)d_ws + (size_t)N_TOK * KF * 2);     // 128 MiB

    quant_x<<<2048, 256, 0, stream>>>(x, scale, A);
    dequant_w<<<2048, 256, 0, stream>>>(packed, signs, minexp, W);
    gemm_bt<<<(N_TOK / BM) * (NF / BN), 512, 0, stream>>>(A, W, bias, scale, out);
}